// Round 6
// baseline (183.860 us; speedup 1.0000x reference)
//
#include <hip/hip_runtime.h>

// ContinuousVariableQNN: out[b,i] = 0.25*(dsum[i] + mux^2 + mup^2) - 0.5
// mu = (2*inputs) @ (S[:,0::2])^T, S = prod_l (C @ D_l) via closed-form C.
// R6: qnn_gemm LDS-free — each wave loads its A-fragments straight from global
// (32 B/lane contiguous), packs to bf16 in-reg, MFMAs vs L2-resident Wb.
// No __syncthreads, occupancy VGPR-limited instead of LDS/barrier-limited.

#define BATCH 131072
#define PSTR 40  // 32 k + 8 pad (shorts); row stride 80 B

typedef __attribute__((ext_vector_type(8))) short bf16x8;
typedef __attribute__((ext_vector_type(4))) float f32x4;

#define MFMA(a, b, c) __builtin_amdgcn_mfma_f32_16x16x32_bf16(a, b, c, 0, 0, 0)

__device__ __forceinline__ unsigned short f2bf(float f) {
  unsigned int u = __float_as_uint(f);
  u += 0x7FFFu + ((u >> 16) & 1u);
  return (unsigned short)(u >> 16);
}
__device__ __forceinline__ float bf2f(unsigned short h) {
  return __uint_as_float(((unsigned int)h) << 16);
}
__device__ __forceinline__ void pack8(const float* v, uint4& hv, uint4& lv) {
  unsigned int hw[4], lw[4];
#pragma unroll
  for (int p = 0; p < 4; ++p) {
    unsigned short h0 = f2bf(v[2 * p]), h1 = f2bf(v[2 * p + 1]);
    unsigned short l0 = f2bf(v[2 * p] - bf2f(h0)), l1 = f2bf(v[2 * p + 1] - bf2f(h1));
    hw[p] = (unsigned int)h0 | ((unsigned int)h1 << 16);
    lw[p] = (unsigned int)l0 | ((unsigned int)l1 << 16);
  }
  hv = make_uint4(hw[0], hw[1], hw[2], hw[3]);
  lv = make_uint4(lw[0], lw[1], lw[2], lw[3]);
}
__device__ __forceinline__ bf16x8 cvt8(f32x4 lo, f32x4 hi) {
  union { unsigned int u[4]; bf16x8 v; } r;
  r.u[0] = (unsigned)f2bf(lo.x) | ((unsigned)f2bf(lo.y) << 16);
  r.u[1] = (unsigned)f2bf(lo.z) | ((unsigned)f2bf(lo.w) << 16);
  r.u[2] = (unsigned)f2bf(hi.x) | ((unsigned)f2bf(hi.y) << 16);
  r.u[3] = (unsigned)f2bf(hi.z) | ((unsigned)f2bf(hi.w) << 16);
  return r.v;
}

// Closed-form C entry magnitude: powc[m] = 2^(-m/2) = c^m.
__device__ __forceinline__ float cxf(const float* powc, int a, int nn) {
  if (a < 127) {
    if (nn == 0) return powc[a + 1];
    if (nn <= a) return powc[a - nn + 2];
    if (nn == a + 1) return -0.70710678118654752f;
    return 0.0f;
  }
  return (nn == 0) ? powc[127] : powc[128 - nn];
}

// ============ K1: P[p] = M[2p+1] @ M[2p], M chunks built in-LDS =============
__global__ __launch_bounds__(256) void l1_prod(const float* __restrict__ params,
                                               unsigned short* __restrict__ Phi,
                                               unsigned short* __restrict__ Plo) {
  __shared__ __align__(16) char lds_raw[4 * 128 * PSTR * 2];  // 40960 B staging / sEp
  __shared__ float blkA[128][4];
  __shared__ float blkB[128][4];
  __shared__ float powc[132];
  unsigned short* sLhi = (unsigned short*)lds_raw;
  unsigned short* sLlo = sLhi + 128 * PSTR;
  unsigned short* sRhi = sLlo + 128 * PSTR;
  unsigned short* sRlo = sRhi + 128 * PSTR;
  float* sEp = (float*)lds_raw;  // epilogue [64][129]

  int bx = blockIdx.x;
  int pair = bx >> 2, tile = bx & 3;
  int tr = tile >> 1, tc = tile & 1;
  int t = threadIdx.x;
  int lane = t & 63, w = t >> 6;
  int wr = (w >> 1) * 64, wc = (w & 1) * 64;
  int l15 = lane & 15, q = lane >> 4;

  {
    int l = (t < 128) ? (2 * pair + 1) : (2 * pair);
    int nn = t & 127;
    const float* p = params + l * 384 + nn * 3;
    float th1 = p[0], r = p[1], th2 = p[2];
    float c1 = cosf(th1), s1 = sinf(th1);
    float c2 = cosf(th2), s2 = sinf(th2);
    float em = expf(-r), ep = expf(r);
    float* dst = (t < 128) ? blkA[nn] : blkB[nn];
    dst[0] = c2 * c1 * em - s2 * s1 * ep;
    dst[1] = -c2 * s1 * em - s2 * c1 * ep;
    dst[2] = s2 * c1 * em + c2 * s1 * ep;
    dst[3] = -s2 * s1 * em + c2 * c1 * ep;
    if (t < 132) powc[t] = exp2f(-0.5f * (float)t);
  }

  f32x4 acc[4][4];
#pragma unroll
  for (int a = 0; a < 4; ++a)
#pragma unroll
    for (int b = 0; b < 4; ++b) acc[a][b] = (f32x4){0.f, 0.f, 0.f, 0.f};

  for (int kc = 0; kc < 256; kc += 32) {
    __syncthreads();
#pragma unroll
    for (int it = 0; it < 2; ++it) {
      int e = it * 2048 + t * 8;
      int row = e >> 5, k0 = e & 31;
      {
        int i = tr * 128 + row;
        int a = i >> 1;
        float vv[8];
#pragma unroll
        for (int jj = 0; jj < 8; ++jj) {
          int j = kc + k0 + jj;
          int nn = j >> 1;
          vv[jj] = cxf(powc, a, nn) * blkA[nn][(i & 1) * 2 + (j & 1)];
        }
        uint4 hv, lv;
        pack8(vv, hv, lv);
        *(uint4*)(sLhi + row * PSTR + k0) = hv;
        *(uint4*)(sLlo + row * PSTR + k0) = lv;
      }
      {
        int j = tc * 128 + row;
        int nn = j >> 1;
        float b0 = blkB[nn][0 + (j & 1)];
        float b1 = blkB[nn][2 + (j & 1)];
        float vv[8];
#pragma unroll
        for (int jj = 0; jj < 8; ++jj) {
          int i = kc + k0 + jj;
          vv[jj] = cxf(powc, i >> 1, nn) * ((i & 1) ? b1 : b0);
        }
        uint4 hv, lv;
        pack8(vv, hv, lv);
        *(uint4*)(sRhi + row * PSTR + k0) = hv;
        *(uint4*)(sRlo + row * PSTR + k0) = lv;
      }
    }
    __syncthreads();
    int kb = q * 8;
    bf16x8 afh[4], afl[4], bfh[4], bfl[4];
#pragma unroll
    for (int rt = 0; rt < 4; ++rt) {
      int r = wr + rt * 16 + l15;
      afh[rt] = *(const bf16x8*)(sLhi + r * PSTR + kb);
      afl[rt] = *(const bf16x8*)(sLlo + r * PSTR + kb);
      int n = wc + rt * 16 + l15;
      bfh[rt] = *(const bf16x8*)(sRhi + n * PSTR + kb);
      bfl[rt] = *(const bf16x8*)(sRlo + n * PSTR + kb);
    }
#pragma unroll
    for (int rt = 0; rt < 4; ++rt)
#pragma unroll
      for (int ct = 0; ct < 4; ++ct) {
        acc[rt][ct] = MFMA(afh[rt], bfh[ct], acc[rt][ct]);
        acc[rt][ct] = MFMA(afh[rt], bfl[ct], acc[rt][ct]);
        acc[rt][ct] = MFMA(afl[rt], bfh[ct], acc[rt][ct]);
      }
  }

  for (int ph = 0; ph < 2; ++ph) {
    __syncthreads();
    if (wr == ph * 64) {
#pragma unroll
      for (int rt = 0; rt < 4; ++rt)
#pragma unroll
        for (int ct = 0; ct < 4; ++ct) {
          int rl = rt * 16 + q * 4;
          int col = wc + ct * 16 + l15;
#pragma unroll
          for (int rg = 0; rg < 4; ++rg) sEp[(rl + rg) * 129 + col] = acc[rt][ct][rg];
        }
    }
    __syncthreads();
    if (pair & 1) {
      int rl = t >> 2, cseg = (t & 3) * 32;
      for (int cc = 0; cc < 32; cc += 8) {
        float v[8];
#pragma unroll
        for (int jj = 0; jj < 8; ++jj) v[jj] = sEp[rl * 129 + cseg + cc + jj];
        uint4 hv, lv;
        pack8(v, hv, lv);
        int off = pair * 65536 + (tr * 128 + ph * 64 + rl) * 256 + tc * 128 + cseg + cc;
        *(uint4*)(Phi + off) = hv;
        *(uint4*)(Plo + off) = lv;
      }
    } else {
      int col = t >> 1, rseg = (t & 1) * 32;
      for (int cc = 0; cc < 32; cc += 8) {
        float v[8];
#pragma unroll
        for (int jj = 0; jj < 8; ++jj) v[jj] = sEp[(rseg + cc + jj) * 129 + col];
        uint4 hv, lv;
        pack8(v, hv, lv);
        int off = pair * 65536 + (tc * 128 + col) * 256 + tr * 128 + ph * 64 + rseg + cc;
        *(uint4*)(Phi + off) = hv;
        *(uint4*)(Plo + off) = lv;
      }
    }
  }
}

// ============ K2: Q[p] = P[2p+1] @ P[2p] (generic, LDS-staged) ==============
__global__ __launch_bounds__(256) void matprod(
    const unsigned short* __restrict__ Lhi_base, const unsigned short* __restrict__ Llo_base,
    unsigned short* __restrict__ Ohi, unsigned short* __restrict__ Olo) {
  __shared__ __align__(16) char lds_raw[4 * 128 * PSTR * 2];
  unsigned short* sLhi = (unsigned short*)lds_raw;
  unsigned short* sLlo = sLhi + 128 * PSTR;
  unsigned short* sRhi = sLlo + 128 * PSTR;
  unsigned short* sRlo = sRhi + 128 * PSTR;
  float* sEp = (float*)lds_raw;

  int bx = blockIdx.x;
  int pair = bx >> 2, tile = bx & 3;
  int tr = tile >> 1, tc = tile & 1;
  const unsigned short* Lhi = Lhi_base + (2 * pair + 1) * 65536;
  const unsigned short* Llo = Llo_base + (2 * pair + 1) * 65536;
  const unsigned short* Rhi = Lhi_base + (2 * pair) * 65536;
  const unsigned short* Rlo = Llo_base + (2 * pair) * 65536;

  int t = threadIdx.x;
  int lane = t & 63, w = t >> 6;
  int wr = (w >> 1) * 64, wc = (w & 1) * 64;
  int l15 = lane & 15, q = lane >> 4;

  f32x4 acc[4][4];
#pragma unroll
  for (int a = 0; a < 4; ++a)
#pragma unroll
    for (int b = 0; b < 4; ++b) acc[a][b] = (f32x4){0.f, 0.f, 0.f, 0.f};

  for (int kc = 0; kc < 256; kc += 32) {
    __syncthreads();
#pragma unroll
    for (int it = 0; it < 2; ++it) {
      int e = it * 2048 + t * 8;
      int row = e >> 5, k = e & 31;
      *(uint4*)(sLhi + row * PSTR + k) = *(const uint4*)(Lhi + (tr * 128 + row) * 256 + kc + k);
      *(uint4*)(sLlo + row * PSTR + k) = *(const uint4*)(Llo + (tr * 128 + row) * 256 + kc + k);
      *(uint4*)(sRhi + row * PSTR + k) = *(const uint4*)(Rhi + (tc * 128 + row) * 256 + kc + k);
      *(uint4*)(sRlo + row * PSTR + k) = *(const uint4*)(Rlo + (tc * 128 + row) * 256 + kc + k);
    }
    __syncthreads();
    int kb = q * 8;
    bf16x8 afh[4], afl[4], bfh[4], bfl[4];
#pragma unroll
    for (int rt = 0; rt < 4; ++rt) {
      int r = wr + rt * 16 + l15;
      afh[rt] = *(const bf16x8*)(sLhi + r * PSTR + kb);
      afl[rt] = *(const bf16x8*)(sLlo + r * PSTR + kb);
      int n = wc + rt * 16 + l15;
      bfh[rt] = *(const bf16x8*)(sRhi + n * PSTR + kb);
      bfl[rt] = *(const bf16x8*)(sRlo + n * PSTR + kb);
    }
#pragma unroll
    for (int rt = 0; rt < 4; ++rt)
#pragma unroll
      for (int ct = 0; ct < 4; ++ct) {
        acc[rt][ct] = MFMA(afh[rt], bfh[ct], acc[rt][ct]);
        acc[rt][ct] = MFMA(afh[rt], bfl[ct], acc[rt][ct]);
        acc[rt][ct] = MFMA(afl[rt], bfh[ct], acc[rt][ct]);
      }
  }

  for (int ph = 0; ph < 2; ++ph) {
    __syncthreads();
    if (wr == ph * 64) {
#pragma unroll
      for (int rt = 0; rt < 4; ++rt)
#pragma unroll
        for (int ct = 0; ct < 4; ++ct) {
          int rl = rt * 16 + q * 4;
          int col = wc + ct * 16 + l15;
#pragma unroll
          for (int rg = 0; rg < 4; ++rg) sEp[(rl + rg) * 129 + col] = acc[rt][ct][rg];
        }
    }
    __syncthreads();
    if (pair & 1) {
      int rl = t >> 2, cseg = (t & 3) * 32;
      for (int cc = 0; cc < 32; cc += 8) {
        float v[8];
#pragma unroll
        for (int jj = 0; jj < 8; ++jj) v[jj] = sEp[rl * 129 + cseg + cc + jj];
        uint4 hv, lv;
        pack8(v, hv, lv);
        int off = pair * 65536 + (tr * 128 + ph * 64 + rl) * 256 + tc * 128 + cseg + cc;
        *(uint4*)(Ohi + off) = hv;
        *(uint4*)(Olo + off) = lv;
      }
    } else {
      int col = t >> 1, rseg = (t & 1) * 32;
      for (int cc = 0; cc < 32; cc += 8) {
        float v[8];
#pragma unroll
        for (int jj = 0; jj < 8; ++jj) v[jj] = sEp[(rseg + cc + jj) * 129 + col];
        uint4 hv, lv;
        pack8(v, hv, lv);
        int off = pair * 65536 + (tc * 128 + col) * 256 + tr * 128 + ph * 64 + rseg + cc;
        *(uint4*)(Ohi + off) = hv;
        *(uint4*)(Olo + off) = lv;
      }
    }
  }
}

// ============ K3: S-tile = Q1 @ Q0, fused pack_W + dsum partials ============
__global__ __launch_bounds__(256) void l3_fused(
    const unsigned short* __restrict__ Qhi, const unsigned short* __restrict__ Qlo,
    unsigned short* __restrict__ Wb, float* __restrict__ dsum_part) {
  __shared__ __align__(16) char lds_raw[4 * 128 * PSTR * 2];
  unsigned short* sLhi = (unsigned short*)lds_raw;
  unsigned short* sLlo = sLhi + 128 * PSTR;
  unsigned short* sRhi = sLlo + 128 * PSTR;
  unsigned short* sRlo = sRhi + 128 * PSTR;
  float* sEp = (float*)lds_raw;  // [64][129]

  int tile = blockIdx.x & 3;
  int tr = tile >> 1, tc = tile & 1;
  const unsigned short* Lhi = Qhi + 65536;
  const unsigned short* Llo = Qlo + 65536;
  const unsigned short* Rhi = Qhi;
  const unsigned short* Rlo = Qlo;

  int t = threadIdx.x;
  int lane = t & 63, w = t >> 6;
  int wr = (w >> 1) * 64, wc = (w & 1) * 64;
  int l15 = lane & 15, q = lane >> 4;

  f32x4 acc[4][4];
#pragma unroll
  for (int a = 0; a < 4; ++a)
#pragma unroll
    for (int b = 0; b < 4; ++b) acc[a][b] = (f32x4){0.f, 0.f, 0.f, 0.f};

  for (int kc = 0; kc < 256; kc += 32) {
    __syncthreads();
#pragma unroll
    for (int it = 0; it < 2; ++it) {
      int e = it * 2048 + t * 8;
      int row = e >> 5, k = e & 31;
      *(uint4*)(sLhi + row * PSTR + k) = *(const uint4*)(Lhi + (tr * 128 + row) * 256 + kc + k);
      *(uint4*)(sLlo + row * PSTR + k) = *(const uint4*)(Llo + (tr * 128 + row) * 256 + kc + k);
      *(uint4*)(sRhi + row * PSTR + k) = *(const uint4*)(Rhi + (tc * 128 + row) * 256 + kc + k);
      *(uint4*)(sRlo + row * PSTR + k) = *(const uint4*)(Rlo + (tc * 128 + row) * 256 + kc + k);
    }
    __syncthreads();
    int kb = q * 8;
    bf16x8 afh[4], afl[4], bfh[4], bfl[4];
#pragma unroll
    for (int rt = 0; rt < 4; ++rt) {
      int r = wr + rt * 16 + l15;
      afh[rt] = *(const bf16x8*)(sLhi + r * PSTR + kb);
      afl[rt] = *(const bf16x8*)(sLlo + r * PSTR + kb);
      int n = wc + rt * 16 + l15;
      bfh[rt] = *(const bf16x8*)(sRhi + n * PSTR + kb);
      bfl[rt] = *(const bf16x8*)(sRlo + n * PSTR + kb);
    }
#pragma unroll
    for (int rt = 0; rt < 4; ++rt)
#pragma unroll
      for (int ct = 0; ct < 4; ++ct) {
        acc[rt][ct] = MFMA(afh[rt], bfh[ct], acc[rt][ct]);
        acc[rt][ct] = MFMA(afh[rt], bfl[ct], acc[rt][ct]);
        acc[rt][ct] = MFMA(afl[rt], bfh[ct], acc[rt][ct]);
      }
  }

  for (int ph = 0; ph < 2; ++ph) {
    __syncthreads();
    if (wr == ph * 64) {
#pragma unroll
      for (int rt = 0; rt < 4; ++rt)
#pragma unroll
        for (int ct = 0; ct < 4; ++ct) {
          int rl = rt * 16 + q * 4;
          int col = wc + ct * 16 + l15;
#pragma unroll
          for (int rg = 0; rg < 4; ++rg) sEp[(rl + rg) * 129 + col] = acc[rt][ct][rg];
        }
    }
    __syncthreads();
    int rbase = tr * 128 + ph * 64;
    int ctbase = tr * 4 + ph * 2;
#pragma unroll
    for (int ci = 0; ci < 2; ++ci) {
      int cell = w * 2 + ci;  // 0..7
      int c2 = cell >> 1;
      int ct = ctbase + (c2 & 1) + ((c2 & 2) ? 8 : 0);
      int ks = 2 * tc + (cell & 1);
      int n = ct * 16 + l15;
      int srow = (n < 128) ? (2 * n) : (2 * (n - 128) + 1);
      int lr = srow - rbase;
      int lc0 = (cell & 1) * 64 + q * 16;
      float v[8];
#pragma unroll
      for (int jj = 0; jj < 8; ++jj) v[jj] = 2.0f * sEp[lr * 129 + lc0 + 2 * jj];
      unsigned int wd[4];
#pragma unroll
      for (int p2 = 0; p2 < 4; ++p2)
        wd[p2] = (unsigned int)f2bf(v[2 * p2]) | ((unsigned int)f2bf(v[2 * p2 + 1]) << 16);
      *(uint4*)(Wb + ((ct * 4 + ks) * 64 + lane) * 8) = make_uint4(wd[0], wd[1], wd[2], wd[3]);
    }
    {
      int ii = t >> 3, s = t & 7;
      int c0 = s * 16;
      float sum = 0.f;
#pragma unroll
      for (int c = 0; c < 16; ++c) {
        float x = sEp[(2 * ii) * 129 + c0 + c];
        float y = sEp[(2 * ii + 1) * 129 + c0 + c];
        sum += x * x + y * y;
      }
      sum += __shfl_down(sum, 4, 8);
      sum += __shfl_down(sum, 2, 8);
      sum += __shfl_down(sum, 1, 8);
      if (s == 0) dsum_part[tc * 128 + (rbase >> 1) + ii] = sum;
    }
  }
}

// ============ K4: LDS-free batched GEMM + fused epilogue ====================
// grid 2048, block 256 = 4 waves (2 row-groups x 2 col-halves); wave = 32 rows
// x 128 cols. A-frags loaded straight from global (32 B/lane contiguous).
__global__ __launch_bounds__(256) void qnn_gemm(
    const float* __restrict__ A, const unsigned short* __restrict__ Wb,
    const float* __restrict__ dsum_part, float* __restrict__ out) {
  int t = threadIdx.x;
  int lane = t & 63, w = t >> 6;
  int wr = w >> 1, wc = w & 1;
  int l15 = lane & 15, q = lane >> 4;
  long brow0 = (long)blockIdx.x * 64;
  long r0 = brow0 + wr * 32 + l15;  // this lane's a0 row; a1 row = r0+16

  float ds[4];
#pragma unroll
  for (int qq = 0; qq < 4; ++qq) {
    int i = (wc * 4 + qq) * 16 + l15;
    ds[qq] = dsum_part[i] + dsum_part[128 + i];
  }

  f32x4 acc[2][4][2];
#pragma unroll
  for (int rt = 0; rt < 2; ++rt)
#pragma unroll
    for (int qq = 0; qq < 4; ++qq)
#pragma unroll
      for (int xp = 0; xp < 2; ++xp) acc[rt][qq][xp] = (f32x4){0.f, 0.f, 0.f, 0.f};

  // Load all A up front (16 f32x4, in flight together), then convert, then MFMA.
  f32x4 af[4][4];  // [ks][0..1]=a0 lo/hi, [2..3]=a1 lo/hi
#pragma unroll
  for (int ks = 0; ks < 4; ++ks) {
    int kb = ks * 32 + q * 8;
    const float* p0 = A + r0 * 128 + kb;
    af[ks][0] = *(const f32x4*)(p0);
    af[ks][1] = *(const f32x4*)(p0 + 4);
    af[ks][2] = *(const f32x4*)(p0 + 2048);  // +16 rows
    af[ks][3] = *(const f32x4*)(p0 + 2052);
  }

#pragma unroll
  for (int ks = 0; ks < 4; ++ks) {
    bf16x8 a0 = cvt8(af[ks][0], af[ks][1]);
    bf16x8 a1 = cvt8(af[ks][2], af[ks][3]);
#pragma unroll
    for (int qq = 0; qq < 4; ++qq)
#pragma unroll
      for (int xp = 0; xp < 2; ++xp) {
        int ct = wc * 4 + qq + 8 * xp;
        bf16x8 b = *(const bf16x8*)(Wb + ((ct * 4 + ks) * 64 + lane) * 8);
        acc[0][qq][xp] = MFMA(a0, b, acc[0][qq][xp]);
        acc[1][qq][xp] = MFMA(a1, b, acc[1][qq][xp]);
      }
  }

  // Fused epilogue: out = 0.25*(dsum + mux^2 + mup^2) - 0.5 (cached stores).
#pragma unroll
  for (int qq = 0; qq < 4; ++qq) {
    int i = (wc * 4 + qq) * 16 + l15;
#pragma unroll
    for (int rt = 0; rt < 2; ++rt) {
      long row0 = brow0 + wr * 32 + rt * 16 + q * 4;
      f32x4 ax = acc[rt][qq][0];
      f32x4 ap = acc[rt][qq][1];
#pragma unroll
      for (int rg = 0; rg < 4; ++rg) {
        out[(row0 + rg) * 128 + i] =
            0.25f * (ds[qq] + ax[rg] * ax[rg] + ap[rg] * ap[rg]) - 0.5f;
      }
    }
  }
}

// ---------------- launcher ----------------------------------------------------
extern "C" void kernel_launch(void* const* d_in, const int* in_sizes, int n_in,
                              void* d_out, int out_size, void* d_ws, size_t ws_size,
                              hipStream_t stream) {
  const float* inputs = (const float*)d_in[0];   // [131072][128] f32
  const float* params = (const float*)d_in[1];   // [8][384] f32
  float* out = (float*)d_out;                    // [131072][128] f32

  unsigned short* Phi = (unsigned short*)d_ws;           // 4*65536
  unsigned short* Plo = Phi + 4 * 65536;
  unsigned short* Qhi = Plo + 4 * 65536;                 // 2*65536
  unsigned short* Qlo = Qhi + 2 * 65536;
  unsigned short* Wb = Qlo + 2 * 65536;                  // 65536
  float* dsum_part = (float*)(Wb + 65536);               // 256 f32

  l1_prod<<<16, 256, 0, stream>>>(params, Phi, Plo);
  matprod<<<8, 256, 0, stream>>>(Phi, Plo, Qhi, Qlo);
  l3_fused<<<4, 256, 0, stream>>>(Qhi, Qlo, Wb, dsum_part);
  qnn_gemm<<<BATCH / 64, 256, 0, stream>>>(inputs, Wb, dsum_part, out);
}

// Round 7
// 180.315 us; speedup vs baseline: 1.0197x; 1.0197x over previous
//
#include <hip/hip_runtime.h>

// ContinuousVariableQNN: out[b,i] = 0.25*(dsum[i] + mux^2 + mup^2) - 0.5
// mu = (2*inputs) @ (S[:,0::2])^T, S = prod_l (C @ D_l) via closed-form C.
// R7: qnn_gemm = persistent LDS-free pipeline. Loop-carried af[] prefetch regs
// force 16 wave-loads in flight across the MFMA block (R6 failed because the
// compiler rolled the loads; VGPR=68 was the tell). No __syncthreads at all.

#define BATCH 131072
#define PSTR 40  // 32 k + 8 pad (shorts); row stride 80 B
#define NCH 4    // chunks of 64 rows per block in qnn_gemm

typedef __attribute__((ext_vector_type(8))) short bf16x8;
typedef __attribute__((ext_vector_type(4))) float f32x4;

#define MFMA(a, b, c) __builtin_amdgcn_mfma_f32_16x16x32_bf16(a, b, c, 0, 0, 0)

__device__ __forceinline__ unsigned short f2bf(float f) {
  unsigned int u = __float_as_uint(f);
  u += 0x7FFFu + ((u >> 16) & 1u);
  return (unsigned short)(u >> 16);
}
__device__ __forceinline__ float bf2f(unsigned short h) {
  return __uint_as_float(((unsigned int)h) << 16);
}
__device__ __forceinline__ void pack8(const float* v, uint4& hv, uint4& lv) {
  unsigned int hw[4], lw[4];
#pragma unroll
  for (int p = 0; p < 4; ++p) {
    unsigned short h0 = f2bf(v[2 * p]), h1 = f2bf(v[2 * p + 1]);
    unsigned short l0 = f2bf(v[2 * p] - bf2f(h0)), l1 = f2bf(v[2 * p + 1] - bf2f(h1));
    hw[p] = (unsigned int)h0 | ((unsigned int)h1 << 16);
    lw[p] = (unsigned int)l0 | ((unsigned int)l1 << 16);
  }
  hv = make_uint4(hw[0], hw[1], hw[2], hw[3]);
  lv = make_uint4(lw[0], lw[1], lw[2], lw[3]);
}
__device__ __forceinline__ bf16x8 cvt8(f32x4 lo, f32x4 hi) {
  union { unsigned int u[4]; bf16x8 v; } r;
  r.u[0] = (unsigned)f2bf(lo.x) | ((unsigned)f2bf(lo.y) << 16);
  r.u[1] = (unsigned)f2bf(lo.z) | ((unsigned)f2bf(lo.w) << 16);
  r.u[2] = (unsigned)f2bf(hi.x) | ((unsigned)f2bf(hi.y) << 16);
  r.u[3] = (unsigned)f2bf(hi.z) | ((unsigned)f2bf(hi.w) << 16);
  return r.v;
}

// Closed-form C entry magnitude: powc[m] = 2^(-m/2) = c^m.
__device__ __forceinline__ float cxf(const float* powc, int a, int nn) {
  if (a < 127) {
    if (nn == 0) return powc[a + 1];
    if (nn <= a) return powc[a - nn + 2];
    if (nn == a + 1) return -0.70710678118654752f;
    return 0.0f;
  }
  return (nn == 0) ? powc[127] : powc[128 - nn];
}

// ============ K1: P[p] = M[2p+1] @ M[2p], M chunks built in-LDS =============
__global__ __launch_bounds__(256) void l1_prod(const float* __restrict__ params,
                                               unsigned short* __restrict__ Phi,
                                               unsigned short* __restrict__ Plo) {
  __shared__ __align__(16) char lds_raw[4 * 128 * PSTR * 2];  // 40960 B staging / sEp
  __shared__ float blkA[128][4];
  __shared__ float blkB[128][4];
  __shared__ float powc[132];
  unsigned short* sLhi = (unsigned short*)lds_raw;
  unsigned short* sLlo = sLhi + 128 * PSTR;
  unsigned short* sRhi = sLlo + 128 * PSTR;
  unsigned short* sRlo = sRhi + 128 * PSTR;
  float* sEp = (float*)lds_raw;  // epilogue [64][129]

  int bx = blockIdx.x;
  int pair = bx >> 2, tile = bx & 3;
  int tr = tile >> 1, tc = tile & 1;
  int t = threadIdx.x;
  int lane = t & 63, w = t >> 6;
  int wr = (w >> 1) * 64, wc = (w & 1) * 64;
  int l15 = lane & 15, q = lane >> 4;

  {
    int l = (t < 128) ? (2 * pair + 1) : (2 * pair);
    int nn = t & 127;
    const float* p = params + l * 384 + nn * 3;
    float th1 = p[0], r = p[1], th2 = p[2];
    float c1 = cosf(th1), s1 = sinf(th1);
    float c2 = cosf(th2), s2 = sinf(th2);
    float em = expf(-r), ep = expf(r);
    float* dst = (t < 128) ? blkA[nn] : blkB[nn];
    dst[0] = c2 * c1 * em - s2 * s1 * ep;
    dst[1] = -c2 * s1 * em - s2 * c1 * ep;
    dst[2] = s2 * c1 * em + c2 * s1 * ep;
    dst[3] = -s2 * s1 * em + c2 * c1 * ep;
    if (t < 132) powc[t] = exp2f(-0.5f * (float)t);
  }

  f32x4 acc[4][4];
#pragma unroll
  for (int a = 0; a < 4; ++a)
#pragma unroll
    for (int b = 0; b < 4; ++b) acc[a][b] = (f32x4){0.f, 0.f, 0.f, 0.f};

  for (int kc = 0; kc < 256; kc += 32) {
    __syncthreads();
#pragma unroll
    for (int it = 0; it < 2; ++it) {
      int e = it * 2048 + t * 8;
      int row = e >> 5, k0 = e & 31;
      {
        int i = tr * 128 + row;
        int a = i >> 1;
        float vv[8];
#pragma unroll
        for (int jj = 0; jj < 8; ++jj) {
          int j = kc + k0 + jj;
          int nn = j >> 1;
          vv[jj] = cxf(powc, a, nn) * blkA[nn][(i & 1) * 2 + (j & 1)];
        }
        uint4 hv, lv;
        pack8(vv, hv, lv);
        *(uint4*)(sLhi + row * PSTR + k0) = hv;
        *(uint4*)(sLlo + row * PSTR + k0) = lv;
      }
      {
        int j = tc * 128 + row;
        int nn = j >> 1;
        float b0 = blkB[nn][0 + (j & 1)];
        float b1 = blkB[nn][2 + (j & 1)];
        float vv[8];
#pragma unroll
        for (int jj = 0; jj < 8; ++jj) {
          int i = kc + k0 + jj;
          vv[jj] = cxf(powc, i >> 1, nn) * ((i & 1) ? b1 : b0);
        }
        uint4 hv, lv;
        pack8(vv, hv, lv);
        *(uint4*)(sRhi + row * PSTR + k0) = hv;
        *(uint4*)(sRlo + row * PSTR + k0) = lv;
      }
    }
    __syncthreads();
    int kb = q * 8;
    bf16x8 afh[4], afl[4], bfh[4], bfl[4];
#pragma unroll
    for (int rt = 0; rt < 4; ++rt) {
      int r = wr + rt * 16 + l15;
      afh[rt] = *(const bf16x8*)(sLhi + r * PSTR + kb);
      afl[rt] = *(const bf16x8*)(sLlo + r * PSTR + kb);
      int n = wc + rt * 16 + l15;
      bfh[rt] = *(const bf16x8*)(sRhi + n * PSTR + kb);
      bfl[rt] = *(const bf16x8*)(sRlo + n * PSTR + kb);
    }
#pragma unroll
    for (int rt = 0; rt < 4; ++rt)
#pragma unroll
      for (int ct = 0; ct < 4; ++ct) {
        acc[rt][ct] = MFMA(afh[rt], bfh[ct], acc[rt][ct]);
        acc[rt][ct] = MFMA(afh[rt], bfl[ct], acc[rt][ct]);
        acc[rt][ct] = MFMA(afl[rt], bfh[ct], acc[rt][ct]);
      }
  }

  for (int ph = 0; ph < 2; ++ph) {
    __syncthreads();
    if (wr == ph * 64) {
#pragma unroll
      for (int rt = 0; rt < 4; ++rt)
#pragma unroll
        for (int ct = 0; ct < 4; ++ct) {
          int rl = rt * 16 + q * 4;
          int col = wc + ct * 16 + l15;
#pragma unroll
          for (int rg = 0; rg < 4; ++rg) sEp[(rl + rg) * 129 + col] = acc[rt][ct][rg];
        }
    }
    __syncthreads();
    if (pair & 1) {
      int rl = t >> 2, cseg = (t & 3) * 32;
      for (int cc = 0; cc < 32; cc += 8) {
        float v[8];
#pragma unroll
        for (int jj = 0; jj < 8; ++jj) v[jj] = sEp[rl * 129 + cseg + cc + jj];
        uint4 hv, lv;
        pack8(v, hv, lv);
        int off = pair * 65536 + (tr * 128 + ph * 64 + rl) * 256 + tc * 128 + cseg + cc;
        *(uint4*)(Phi + off) = hv;
        *(uint4*)(Plo + off) = lv;
      }
    } else {
      int col = t >> 1, rseg = (t & 1) * 32;
      for (int cc = 0; cc < 32; cc += 8) {
        float v[8];
#pragma unroll
        for (int jj = 0; jj < 8; ++jj) v[jj] = sEp[(rseg + cc + jj) * 129 + col];
        uint4 hv, lv;
        pack8(v, hv, lv);
        int off = pair * 65536 + (tc * 128 + col) * 256 + tr * 128 + ph * 64 + rseg + cc;
        *(uint4*)(Phi + off) = hv;
        *(uint4*)(Plo + off) = lv;
      }
    }
  }
}

// ============ K2: Q[p] = P[2p+1] @ P[2p] (generic, LDS-staged) ==============
__global__ __launch_bounds__(256) void matprod(
    const unsigned short* __restrict__ Lhi_base, const unsigned short* __restrict__ Llo_base,
    unsigned short* __restrict__ Ohi, unsigned short* __restrict__ Olo) {
  __shared__ __align__(16) char lds_raw[4 * 128 * PSTR * 2];
  unsigned short* sLhi = (unsigned short*)lds_raw;
  unsigned short* sLlo = sLhi + 128 * PSTR;
  unsigned short* sRhi = sLlo + 128 * PSTR;
  unsigned short* sRlo = sRhi + 128 * PSTR;
  float* sEp = (float*)lds_raw;

  int bx = blockIdx.x;
  int pair = bx >> 2, tile = bx & 3;
  int tr = tile >> 1, tc = tile & 1;
  const unsigned short* Lhi = Lhi_base + (2 * pair + 1) * 65536;
  const unsigned short* Llo = Llo_base + (2 * pair + 1) * 65536;
  const unsigned short* Rhi = Lhi_base + (2 * pair) * 65536;
  const unsigned short* Rlo = Llo_base + (2 * pair) * 65536;

  int t = threadIdx.x;
  int lane = t & 63, w = t >> 6;
  int wr = (w >> 1) * 64, wc = (w & 1) * 64;
  int l15 = lane & 15, q = lane >> 4;

  f32x4 acc[4][4];
#pragma unroll
  for (int a = 0; a < 4; ++a)
#pragma unroll
    for (int b = 0; b < 4; ++b) acc[a][b] = (f32x4){0.f, 0.f, 0.f, 0.f};

  for (int kc = 0; kc < 256; kc += 32) {
    __syncthreads();
#pragma unroll
    for (int it = 0; it < 2; ++it) {
      int e = it * 2048 + t * 8;
      int row = e >> 5, k = e & 31;
      *(uint4*)(sLhi + row * PSTR + k) = *(const uint4*)(Lhi + (tr * 128 + row) * 256 + kc + k);
      *(uint4*)(sLlo + row * PSTR + k) = *(const uint4*)(Llo + (tr * 128 + row) * 256 + kc + k);
      *(uint4*)(sRhi + row * PSTR + k) = *(const uint4*)(Rhi + (tc * 128 + row) * 256 + kc + k);
      *(uint4*)(sRlo + row * PSTR + k) = *(const uint4*)(Rlo + (tc * 128 + row) * 256 + kc + k);
    }
    __syncthreads();
    int kb = q * 8;
    bf16x8 afh[4], afl[4], bfh[4], bfl[4];
#pragma unroll
    for (int rt = 0; rt < 4; ++rt) {
      int r = wr + rt * 16 + l15;
      afh[rt] = *(const bf16x8*)(sLhi + r * PSTR + kb);
      afl[rt] = *(const bf16x8*)(sLlo + r * PSTR + kb);
      int n = wc + rt * 16 + l15;
      bfh[rt] = *(const bf16x8*)(sRhi + n * PSTR + kb);
      bfl[rt] = *(const bf16x8*)(sRlo + n * PSTR + kb);
    }
#pragma unroll
    for (int rt = 0; rt < 4; ++rt)
#pragma unroll
      for (int ct = 0; ct < 4; ++ct) {
        acc[rt][ct] = MFMA(afh[rt], bfh[ct], acc[rt][ct]);
        acc[rt][ct] = MFMA(afh[rt], bfl[ct], acc[rt][ct]);
        acc[rt][ct] = MFMA(afl[rt], bfh[ct], acc[rt][ct]);
      }
  }

  for (int ph = 0; ph < 2; ++ph) {
    __syncthreads();
    if (wr == ph * 64) {
#pragma unroll
      for (int rt = 0; rt < 4; ++rt)
#pragma unroll
        for (int ct = 0; ct < 4; ++ct) {
          int rl = rt * 16 + q * 4;
          int col = wc + ct * 16 + l15;
#pragma unroll
          for (int rg = 0; rg < 4; ++rg) sEp[(rl + rg) * 129 + col] = acc[rt][ct][rg];
        }
    }
    __syncthreads();
    if (pair & 1) {
      int rl = t >> 2, cseg = (t & 3) * 32;
      for (int cc = 0; cc < 32; cc += 8) {
        float v[8];
#pragma unroll
        for (int jj = 0; jj < 8; ++jj) v[jj] = sEp[rl * 129 + cseg + cc + jj];
        uint4 hv, lv;
        pack8(v, hv, lv);
        int off = pair * 65536 + (tr * 128 + ph * 64 + rl) * 256 + tc * 128 + cseg + cc;
        *(uint4*)(Ohi + off) = hv;
        *(uint4*)(Olo + off) = lv;
      }
    } else {
      int col = t >> 1, rseg = (t & 1) * 32;
      for (int cc = 0; cc < 32; cc += 8) {
        float v[8];
#pragma unroll
        for (int jj = 0; jj < 8; ++jj) v[jj] = sEp[(rseg + cc + jj) * 129 + col];
        uint4 hv, lv;
        pack8(v, hv, lv);
        int off = pair * 65536 + (tc * 128 + col) * 256 + tr * 128 + ph * 64 + rseg + cc;
        *(uint4*)(Ohi + off) = hv;
        *(uint4*)(Olo + off) = lv;
      }
    }
  }
}

// ============ K3: S-tile = Q1 @ Q0, fused pack_W + dsum partials ============
__global__ __launch_bounds__(256) void l3_fused(
    const unsigned short* __restrict__ Qhi, const unsigned short* __restrict__ Qlo,
    unsigned short* __restrict__ Wb, float* __restrict__ dsum_part) {
  __shared__ __align__(16) char lds_raw[4 * 128 * PSTR * 2];
  unsigned short* sLhi = (unsigned short*)lds_raw;
  unsigned short* sLlo = sLhi + 128 * PSTR;
  unsigned short* sRhi = sLlo + 128 * PSTR;
  unsigned short* sRlo = sRhi + 128 * PSTR;
  float* sEp = (float*)lds_raw;  // [64][129]

  int tile = blockIdx.x & 3;
  int tr = tile >> 1, tc = tile & 1;
  const unsigned short* Lhi = Qhi + 65536;
  const unsigned short* Llo = Qlo + 65536;
  const unsigned short* Rhi = Qhi;
  const unsigned short* Rlo = Qlo;

  int t = threadIdx.x;
  int lane = t & 63, w = t >> 6;
  int wr = (w >> 1) * 64, wc = (w & 1) * 64;
  int l15 = lane & 15, q = lane >> 4;

  f32x4 acc[4][4];
#pragma unroll
  for (int a = 0; a < 4; ++a)
#pragma unroll
    for (int b = 0; b < 4; ++b) acc[a][b] = (f32x4){0.f, 0.f, 0.f, 0.f};

  for (int kc = 0; kc < 256; kc += 32) {
    __syncthreads();
#pragma unroll
    for (int it = 0; it < 2; ++it) {
      int e = it * 2048 + t * 8;
      int row = e >> 5, k = e & 31;
      *(uint4*)(sLhi + row * PSTR + k) = *(const uint4*)(Lhi + (tr * 128 + row) * 256 + kc + k);
      *(uint4*)(sLlo + row * PSTR + k) = *(const uint4*)(Llo + (tr * 128 + row) * 256 + kc + k);
      *(uint4*)(sRhi + row * PSTR + k) = *(const uint4*)(Rhi + (tc * 128 + row) * 256 + kc + k);
      *(uint4*)(sRlo + row * PSTR + k) = *(const uint4*)(Rlo + (tc * 128 + row) * 256 + kc + k);
    }
    __syncthreads();
    int kb = q * 8;
    bf16x8 afh[4], afl[4], bfh[4], bfl[4];
#pragma unroll
    for (int rt = 0; rt < 4; ++rt) {
      int r = wr + rt * 16 + l15;
      afh[rt] = *(const bf16x8*)(sLhi + r * PSTR + kb);
      afl[rt] = *(const bf16x8*)(sLlo + r * PSTR + kb);
      int n = wc + rt * 16 + l15;
      bfh[rt] = *(const bf16x8*)(sRhi + n * PSTR + kb);
      bfl[rt] = *(const bf16x8*)(sRlo + n * PSTR + kb);
    }
#pragma unroll
    for (int rt = 0; rt < 4; ++rt)
#pragma unroll
      for (int ct = 0; ct < 4; ++ct) {
        acc[rt][ct] = MFMA(afh[rt], bfh[ct], acc[rt][ct]);
        acc[rt][ct] = MFMA(afh[rt], bfl[ct], acc[rt][ct]);
        acc[rt][ct] = MFMA(afl[rt], bfh[ct], acc[rt][ct]);
      }
  }

  for (int ph = 0; ph < 2; ++ph) {
    __syncthreads();
    if (wr == ph * 64) {
#pragma unroll
      for (int rt = 0; rt < 4; ++rt)
#pragma unroll
        for (int ct = 0; ct < 4; ++ct) {
          int rl = rt * 16 + q * 4;
          int col = wc + ct * 16 + l15;
#pragma unroll
          for (int rg = 0; rg < 4; ++rg) sEp[(rl + rg) * 129 + col] = acc[rt][ct][rg];
        }
    }
    __syncthreads();
    int rbase = tr * 128 + ph * 64;
    int ctbase = tr * 4 + ph * 2;
#pragma unroll
    for (int ci = 0; ci < 2; ++ci) {
      int cell = w * 2 + ci;  // 0..7
      int c2 = cell >> 1;
      int ct = ctbase + (c2 & 1) + ((c2 & 2) ? 8 : 0);
      int ks = 2 * tc + (cell & 1);
      int n = ct * 16 + l15;
      int srow = (n < 128) ? (2 * n) : (2 * (n - 128) + 1);
      int lr = srow - rbase;
      int lc0 = (cell & 1) * 64 + q * 16;
      float v[8];
#pragma unroll
      for (int jj = 0; jj < 8; ++jj) v[jj] = 2.0f * sEp[lr * 129 + lc0 + 2 * jj];
      unsigned int wd[4];
#pragma unroll
      for (int p2 = 0; p2 < 4; ++p2)
        wd[p2] = (unsigned int)f2bf(v[2 * p2]) | ((unsigned int)f2bf(v[2 * p2 + 1]) << 16);
      *(uint4*)(Wb + ((ct * 4 + ks) * 64 + lane) * 8) = make_uint4(wd[0], wd[1], wd[2], wd[3]);
    }
    {
      int ii = t >> 3, s = t & 7;
      int c0 = s * 16;
      float sum = 0.f;
#pragma unroll
      for (int c = 0; c < 16; ++c) {
        float x = sEp[(2 * ii) * 129 + c0 + c];
        float y = sEp[(2 * ii + 1) * 129 + c0 + c];
        sum += x * x + y * y;
      }
      sum += __shfl_down(sum, 4, 8);
      sum += __shfl_down(sum, 2, 8);
      sum += __shfl_down(sum, 1, 8);
      if (s == 0) dsum_part[tc * 128 + (rbase >> 1) + ii] = sum;
    }
  }
}

// ============ K4: persistent LDS-free GEMM + fused epilogue =================
// grid 512, block 256 = 4 waves; wave = 32 rows x 128 cols per chunk, NCH=4
// chunks. af[] is loop-carried -> compiler must keep 16 loads in flight
// across the MFMA block. No LDS, no __syncthreads.
__global__ __launch_bounds__(256) void qnn_gemm(
    const float* __restrict__ A, const unsigned short* __restrict__ Wb,
    const float* __restrict__ dsum_part, float* __restrict__ out) {
  int t = threadIdx.x;
  int lane = t & 63, w = t >> 6;
  int wr = w >> 1, wc = w & 1;
  int l15 = lane & 15, q = lane >> 4;
  long chunk0 = (long)blockIdx.x * NCH;
  long r0 = chunk0 * 64 + wr * 32 + l15;  // lane's a0 row of chunk 0

  float ds[4];
#pragma unroll
  for (int qq = 0; qq < 4; ++qq) {
    int i = (wc * 4 + qq) * 16 + l15;
    ds[qq] = dsum_part[i] + dsum_part[128 + i];
  }

  // Preload chunk 0 fragments (f32).
  f32x4 af[4][4];  // [ks][0..1]=a0 lo/hi, [2..3]=a1 lo/hi
  {
    const float* p0 = A + r0 * 128;
#pragma unroll
    for (int ks = 0; ks < 4; ++ks) {
      int kb = ks * 32 + q * 8;
      af[ks][0] = *(const f32x4*)(p0 + kb);
      af[ks][1] = *(const f32x4*)(p0 + kb + 4);
      af[ks][2] = *(const f32x4*)(p0 + kb + 2048);  // +16 rows
      af[ks][3] = *(const f32x4*)(p0 + kb + 2052);
    }
  }

#pragma unroll 1
  for (int c = 0; c < NCH; ++c) {
    long brow0 = (chunk0 + c) * 64;

    // Convert current chunk to bf16 frags (consumes af; waitcnt lands here).
    bf16x8 a0f[4], a1f[4];
#pragma unroll
    for (int ks = 0; ks < 4; ++ks) {
      a0f[ks] = cvt8(af[ks][0], af[ks][1]);
      a1f[ks] = cvt8(af[ks][2], af[ks][3]);
    }

    // Issue next chunk's loads; they stay in flight under the MFMA block.
    if (c + 1 < NCH) {
      const float* pn = A + (r0 + (long)(c + 1) * 64) * 128;
#pragma unroll
      for (int ks = 0; ks < 4; ++ks) {
        int kb = ks * 32 + q * 8;
        af[ks][0] = *(const f32x4*)(pn + kb);
        af[ks][1] = *(const f32x4*)(pn + kb + 4);
        af[ks][2] = *(const f32x4*)(pn + kb + 2048);
        af[ks][3] = *(const f32x4*)(pn + kb + 2052);
      }
    }

    f32x4 acc[2][4][2];
#pragma unroll
    for (int rt = 0; rt < 2; ++rt)
#pragma unroll
      for (int qq = 0; qq < 4; ++qq)
#pragma unroll
        for (int xp = 0; xp < 2; ++xp) acc[rt][qq][xp] = (f32x4){0.f, 0.f, 0.f, 0.f};

#pragma unroll
    for (int ks = 0; ks < 4; ++ks) {
#pragma unroll
      for (int qq = 0; qq < 4; ++qq)
#pragma unroll
        for (int xp = 0; xp < 2; ++xp) {
          int ct = wc * 4 + qq + 8 * xp;
          bf16x8 b = *(const bf16x8*)(Wb + ((ct * 4 + ks) * 64 + lane) * 8);
          acc[0][qq][xp] = MFMA(a0f[ks], b, acc[0][qq][xp]);
          acc[1][qq][xp] = MFMA(a1f[ks], b, acc[1][qq][xp]);
        }
    }

    // Fused epilogue (cached stores; L2 combines full lines).
#pragma unroll
    for (int qq = 0; qq < 4; ++qq) {
      int i = (wc * 4 + qq) * 16 + l15;
#pragma unroll
      for (int rt = 0; rt < 2; ++rt) {
        long row0 = brow0 + wr * 32 + rt * 16 + q * 4;
        f32x4 ax = acc[rt][qq][0];
        f32x4 ap = acc[rt][qq][1];
#pragma unroll
        for (int rg = 0; rg < 4; ++rg) {
          out[(row0 + rg) * 128 + i] =
              0.25f * (ds[qq] + ax[rg] * ax[rg] + ap[rg] * ap[rg]) - 0.5f;
        }
      }
    }
  }
}

// ---------------- launcher ----------------------------------------------------
extern "C" void kernel_launch(void* const* d_in, const int* in_sizes, int n_in,
                              void* d_out, int out_size, void* d_ws, size_t ws_size,
                              hipStream_t stream) {
  const float* inputs = (const float*)d_in[0];   // [131072][128] f32
  const float* params = (const float*)d_in[1];   // [8][384] f32
  float* out = (float*)d_out;                    // [131072][128] f32

  unsigned short* Phi = (unsigned short*)d_ws;           // 4*65536
  unsigned short* Plo = Phi + 4 * 65536;
  unsigned short* Qhi = Plo + 4 * 65536;                 // 2*65536
  unsigned short* Qlo = Qhi + 2 * 65536;
  unsigned short* Wb = Qlo + 2 * 65536;                  // 65536
  float* dsum_part = (float*)(Wb + 65536);               // 256 f32

  l1_prod<<<16, 256, 0, stream>>>(params, Phi, Plo);
  matprod<<<8, 256, 0, stream>>>(Phi, Plo, Qhi, Qlo);
  l3_fused<<<4, 256, 0, stream>>>(Qhi, Qlo, Wb, dsum_part);
  qnn_gemm<<<BATCH / (64 * NCH), 256, 0, stream>>>(inputs, Wb, dsum_part, out);
}